// Round 1
// baseline (1743.335 us; speedup 1.0000x reference)
//
#include <hip/hip_runtime.h>
#include <math.h>

#define NB 8
#define NPTS 4096
#define NCH 64
#define NOUT 64
#define KNN 16

// ws layout in floats:
#define WS_SQ  0
#define WS_PT  (NB*NPTS)                       // 32768
#define WS_QT  (WS_PT + NB*NPTS*64)            // + 2097152
#define WS_IDX (WS_QT + NB*NPTS*64)            // int32 region, NB*NPTS*16 ints

// ---------------------------------------------------------------- K1: sq ----
__global__ __launch_bounds__(256) void k_sq(const float* __restrict__ fea,
                                            float* __restrict__ sq) {
    int g = blockIdx.x * 256 + threadIdx.x;      // 32768
    int b = g >> 12, n = g & 4095;
    const float* f = fea + (size_t)b * NCH * NPTS + n;
    float s = 0.f;
#pragma unroll
    for (int c = 0; c < NCH; ++c) s = fmaf(f[c * NPTS], f[c * NPTS], s);
    sq[g] = s;
}

// ------------------------------------------------------- K2: fused KNN ------
__global__ __launch_bounds__(256) void k_knn(const float* __restrict__ fea,
                                             const float* __restrict__ sq,
                                             int* __restrict__ idxout) {
    __shared__ __align__(16) float rowT[64][64];   // [c][r]
    __shared__ __align__(16) float colT[64][64];   // [c][j]
    __shared__ __align__(16) float dist[64][68];   // [r][j] padded
    __shared__ float tkv[64][KNN];
    __shared__ int   tki[64][KNN];

    const int b = blockIdx.y;
    const int n0 = blockIdx.x * 64;
    const int tid = threadIdx.x;
    const int to = tid & 15, tp = tid >> 4;
    const float* feab = fea + (size_t)b * NCH * NPTS;

#pragma unroll
    for (int i = 0; i < 4; ++i) {
        int e = i * 1024 + tid * 4;
        int c = e >> 6, r = e & 63;
        *(float4*)&rowT[c][r] = *(const float4*)&feab[c * NPTS + n0 + r];
    }
    if (tid < 64) {
#pragma unroll
        for (int i = 0; i < KNN; ++i) { tkv[tid][i] = -3.0e38f; tki[tid][i] = 0; }
    }

    for (int m0 = 0; m0 < NPTS; m0 += 64) {
#pragma unroll
        for (int i = 0; i < 4; ++i) {
            int e = i * 1024 + tid * 4;
            int c = e >> 6, j = e & 63;
            *(float4*)&colT[c][j] = *(const float4*)&feab[c * NPTS + m0 + j];
        }
        __syncthreads();

        float acc[4][4] = {{0.f,0.f,0.f,0.f},{0.f,0.f,0.f,0.f},
                           {0.f,0.f,0.f,0.f},{0.f,0.f,0.f,0.f}};
#pragma unroll 8
        for (int c = 0; c < 64; ++c) {
            float4 rv = *(const float4*)&rowT[c][to * 4];
            float4 cv = *(const float4*)&colT[c][tp * 4];
            float rr[4] = {rv.x, rv.y, rv.z, rv.w};
            float cc[4] = {cv.x, cv.y, cv.z, cv.w};
#pragma unroll
            for (int ri = 0; ri < 4; ++ri)
#pragma unroll
                for (int ci = 0; ci < 4; ++ci)
                    acc[ri][ci] = fmaf(rr[ri], cc[ci], acc[ri][ci]);
        }
        float4 sqc = *(const float4*)&sq[b * NPTS + m0 + tp * 4];
        float sqa[4] = {sqc.x, sqc.y, sqc.z, sqc.w};
#pragma unroll
        for (int ri = 0; ri < 4; ++ri) {
            float4 o;
            o.x = 2.f * acc[ri][0] - sqa[0];
            o.y = 2.f * acc[ri][1] - sqa[1];
            o.z = 2.f * acc[ri][2] - sqa[2];
            o.w = 2.f * acc[ri][3] - sqa[3];
            *(float4*)&dist[to * 4 + ri][tp * 4] = o;
        }
        __syncthreads();

        if (tid < 64) {          // wave 0: one thread per row, threshold filter
            const int r = tid;
            float thr = tkv[r][0];
            for (int jj = 0; jj < 64; ++jj) {
                int j = (jj + r) & 63;             // bank-spread scan
                float v = dist[r][j];
                if (v > thr) {
                    int col = m0 + j;
                    int p = 0;
                    while (p < KNN - 1 && tkv[r][p + 1] < v) {
                        tkv[r][p] = tkv[r][p + 1];
                        tki[r][p] = tki[r][p + 1];
                        ++p;
                    }
                    tkv[r][p] = v; tki[r][p] = col;
                    thr = tkv[r][0];
                }
            }
        }
    }
    __syncthreads();
    if (tid < 64) {
        const int r = tid;
#pragma unroll
        for (int i = 0; i < KNN; ++i)
            idxout[((size_t)(b * NPTS + n0 + r)) * KNN + i] = tki[r][i];
    }
}

// ----------------------------------------------- K3: P/Q precompute ---------
__global__ __launch_bounds__(256) void k_pq(const float* __restrict__ fea,
                                            const float* __restrict__ Wf1,
                                            const float* __restrict__ bf1,
                                            float* __restrict__ Pt,
                                            float* __restrict__ Qt) {
    __shared__ __align__(16) float feaT[64][64];    // [c][n]
    __shared__ __align__(16) float WT[64][132];     // [c][o'], o' in 0..127
    __shared__ float sb[64];

    const int b = blockIdx.y;
    const int n0 = blockIdx.x * 64;
    const int tid = threadIdx.x;
    const int to = tid & 15, tn = tid >> 4;
    const float* feab = fea + (size_t)b * NCH * NPTS;

#pragma unroll
    for (int i = 0; i < 4; ++i) {
        int e = i * 1024 + tid * 4;
        int c = e >> 6, nn = e & 63;
        *(float4*)&feaT[c][nn] = *(const float4*)&feab[c * NPTS + n0 + nn];
    }
#pragma unroll
    for (int i = 0; i < 8; ++i) {
        int g = tid * 32 + i * 4;
        int op = g >> 6, c = g & 63;
        const float* src = (op < 64) ? &Wf1[op * 128 + c]
                                     : &Wf1[(op - 64) * 128 + 64 + c];
        float4 w = *(const float4*)src;
        WT[c + 0][op] = w.x; WT[c + 1][op] = w.y;
        WT[c + 2][op] = w.z; WT[c + 3][op] = w.w;
    }
    if (tid < 64) sb[tid] = bf1[tid];
    __syncthreads();

    float acc[4][8];
#pragma unroll
    for (int ni = 0; ni < 4; ++ni)
#pragma unroll
        for (int oj = 0; oj < 8; ++oj) acc[ni][oj] = 0.f;

#pragma unroll 4
    for (int c = 0; c < 64; ++c) {
        float4 a  = *(const float4*)&feaT[c][tn * 4];
        float4 w0 = *(const float4*)&WT[c][to * 8];
        float4 w1 = *(const float4*)&WT[c][to * 8 + 4];
        float av[4] = {a.x, a.y, a.z, a.w};
        float wv[8] = {w0.x, w0.y, w0.z, w0.w, w1.x, w1.y, w1.z, w1.w};
#pragma unroll
        for (int ni = 0; ni < 4; ++ni)
#pragma unroll
            for (int oj = 0; oj < 8; ++oj)
                acc[ni][oj] = fmaf(av[ni], wv[oj], acc[ni][oj]);
    }

    const int opb = to * 8;
#pragma unroll
    for (int ni = 0; ni < 4; ++ni) {
        int n = n0 + tn * 4 + ni;
        size_t base = ((size_t)b * NPTS + n) * 64;
        if (opb < 64) {     // P half: add bias
            float4 o0, o1;
            o0.x = acc[ni][0] + sb[opb + 0]; o0.y = acc[ni][1] + sb[opb + 1];
            o0.z = acc[ni][2] + sb[opb + 2]; o0.w = acc[ni][3] + sb[opb + 3];
            o1.x = acc[ni][4] + sb[opb + 4]; o1.y = acc[ni][5] + sb[opb + 5];
            o1.z = acc[ni][6] + sb[opb + 6]; o1.w = acc[ni][7] + sb[opb + 7];
            *(float4*)&Pt[base + opb]     = o0;
            *(float4*)&Pt[base + opb + 4] = o1;
        } else {            // Q half: no bias
            float4 o0, o1;
            o0.x = acc[ni][0]; o0.y = acc[ni][1]; o0.z = acc[ni][2]; o0.w = acc[ni][3];
            o1.x = acc[ni][4]; o1.y = acc[ni][5]; o1.z = acc[ni][6]; o1.w = acc[ni][7];
            *(float4*)&Qt[base + opb - 64]     = o0;
            *(float4*)&Qt[base + opb - 64 + 4] = o1;
        }
    }
}

// -------------------------------------------- K4: fused MLP + max ----------
__global__ __launch_bounds__(256) void k_mlp(
    const float* __restrict__ xyz,
    const float* __restrict__ Pt, const float* __restrict__ Qt,
    const int* __restrict__ knnidx,
    const float* __restrict__ Wg1, const float* __restrict__ bg1,
    const float* __restrict__ Wg2, const float* __restrict__ bg2,
    const float* __restrict__ Wf2, const float* __restrict__ bf2,
    const float* __restrict__ Wf3, const float* __restrict__ bf3,
    float* __restrict__ out) {
    __shared__ __align__(16) float bufX[64][68];
    __shared__ __align__(16) float bufY[64][68];
    __shared__ __align__(16) float Wbuf[64][68];
    __shared__ __align__(16) float scratch[1280];  // geo[10][68] then pm[64][17]
    __shared__ float biasS[64];
    __shared__ int sidx[64];

    const int b = blockIdx.y;
    const int n0 = blockIdx.x * 4;
    const int tid = threadIdx.x;
    const int to = tid & 15, tp = tid >> 4;

    if (tid < 64)
        sidx[tid] = knnidx[((size_t)(b * NPTS + n0)) * KNN + tid];
    __syncthreads();

    // f1 = relu(P + Q_gather) into bufX [c][pair]
    {
        int pair = tid >> 2, q = tid & 3;
        int m = sidx[pair];
        int pt = pair >> 4;
        const float* pB = &Pt[((size_t)b * NPTS + n0 + pt) * 64];
        const float* qB = &Qt[((size_t)b * NPTS + m) * 64];
#pragma unroll
        for (int i = 0; i < 4; ++i) {
            int c0 = q * 16 + i * 4;
            float4 pv = *(const float4*)&pB[c0];
            float4 qv = *(const float4*)&qB[c0];
            bufX[c0 + 0][pair] = fmaxf(pv.x + qv.x, 0.f);
            bufX[c0 + 1][pair] = fmaxf(pv.y + qv.y, 0.f);
            bufX[c0 + 2][pair] = fmaxf(pv.z + qv.z, 0.f);
            bufX[c0 + 3][pair] = fmaxf(pv.w + qv.w, 0.f);
        }
    }
    // geo [10][68] into scratch
    if (tid < 64) {
        int pair = tid, pt = pair >> 4;
        int m = sidx[pair];
        const float* xb = xyz + (size_t)b * 3 * NPTS;
        float cx = xb[0 * NPTS + n0 + pt], cy = xb[1 * NPTS + n0 + pt], cz = xb[2 * NPTS + n0 + pt];
        float kx = xb[0 * NPTS + m], ky = xb[1 * NPTS + m], kz = xb[2 * NPTS + m];
        float rx = cx - kx, ry = cy - ky, rz = cz - kz;
        float d = sqrtf(rx * rx + ry * ry + rz * rz);
        scratch[0 * 68 + pair] = d;
        scratch[1 * 68 + pair] = cx; scratch[2 * 68 + pair] = cy; scratch[3 * 68 + pair] = cz;
        scratch[4 * 68 + pair] = kx; scratch[5 * 68 + pair] = ky; scratch[6 * 68 + pair] = kz;
        scratch[7 * 68 + pair] = rx; scratch[8 * 68 + pair] = ry; scratch[9 * 68 + pair] = rz;
    }

    auto stageW = [&](const float* W, const float* bv) {
#pragma unroll
        for (int i = 0; i < 4; ++i) {
            int g = tid * 16 + i * 4;
            int o = g >> 6, c = g & 63;
            float4 w = *(const float4*)&W[g];
            Wbuf[c + 0][o] = w.x; Wbuf[c + 1][o] = w.y;
            Wbuf[c + 2][o] = w.z; Wbuf[c + 3][o] = w.w;
        }
        if (tid < 64) biasS[tid] = bv[tid];
    };

    auto gemmPh = [&](const float* src, float* dst, int Kdim) {
        float acc[4][4] = {{0.f,0.f,0.f,0.f},{0.f,0.f,0.f,0.f},
                           {0.f,0.f,0.f,0.f},{0.f,0.f,0.f,0.f}};
#pragma unroll 2
        for (int c = 0; c < Kdim; ++c) {
            float4 w = *(const float4*)&Wbuf[c][to * 4];
            float4 a = *(const float4*)(src + c * 68 + tp * 4);
            float wr[4] = {w.x, w.y, w.z, w.w};
            float ar[4] = {a.x, a.y, a.z, a.w};
#pragma unroll
            for (int oi = 0; oi < 4; ++oi)
#pragma unroll
                for (int pj = 0; pj < 4; ++pj)
                    acc[oi][pj] = fmaf(wr[oi], ar[pj], acc[oi][pj]);
        }
#pragma unroll
        for (int oi = 0; oi < 4; ++oi) {
            float bo = biasS[to * 4 + oi];
            float4 o4;
            o4.x = fmaxf(acc[oi][0] + bo, 0.f);
            o4.y = fmaxf(acc[oi][1] + bo, 0.f);
            o4.z = fmaxf(acc[oi][2] + bo, 0.f);
            o4.w = fmaxf(acc[oi][3] + bo, 0.f);
            *(float4*)(dst + (to * 4 + oi) * 68 + tp * 4) = o4;
        }
    };

    stageW(Wf2, bf2);
    __syncthreads();
    gemmPh(&bufX[0][0], &bufY[0][0], 64);       // f2
    __syncthreads();
    stageW(Wf3, bf3);
    __syncthreads();
    gemmPh(&bufY[0][0], &bufX[0][0], 64);       // f3 -> bufX
    __syncthreads();
    {   // Wg1 is 64x10
        for (int e = tid; e < 640; e += 256) {
            int o = e / 10, c = e - o * 10;
            Wbuf[c][o] = Wg1[e];
        }
        if (tid < 64) biasS[tid] = bg1[tid];
    }
    __syncthreads();
    gemmPh(scratch, &bufY[0][0], 10);           // g1 -> bufY
    __syncthreads();
    stageW(Wg2, bg2);
    __syncthreads();
    {   // g2 GEMM with fused *f3 and partial max epilogue
        float acc[4][4] = {{0.f,0.f,0.f,0.f},{0.f,0.f,0.f,0.f},
                           {0.f,0.f,0.f,0.f},{0.f,0.f,0.f,0.f}};
#pragma unroll 2
        for (int c = 0; c < 64; ++c) {
            float4 w = *(const float4*)&Wbuf[c][to * 4];
            float4 a = *(const float4*)&bufY[c][tp * 4];
            float wr[4] = {w.x, w.y, w.z, w.w};
            float ar[4] = {a.x, a.y, a.z, a.w};
#pragma unroll
            for (int oi = 0; oi < 4; ++oi)
#pragma unroll
                for (int pj = 0; pj < 4; ++pj)
                    acc[oi][pj] = fmaf(wr[oi], ar[pj], acc[oi][pj]);
        }
#pragma unroll
        for (int oi = 0; oi < 4; ++oi) {
            int o = to * 4 + oi;
            float bo = biasS[o];
            float mx = -3.0e38f;
#pragma unroll
            for (int pj = 0; pj < 4; ++pj) {
                float g2v = fmaxf(acc[oi][pj] + bo, 0.f);
                float f3v = bufX[o][tp * 4 + pj];
                mx = fmaxf(mx, g2v * f3v);
            }
            scratch[o * 17 + tp] = mx;          // pm[64][17]
        }
    }
    __syncthreads();
    {
        int o = tid & 63, pt = tid >> 6;
        float m0_ = scratch[o * 17 + pt * 4 + 0];
        float m1  = scratch[o * 17 + pt * 4 + 1];
        float m2  = scratch[o * 17 + pt * 4 + 2];
        float m3  = scratch[o * 17 + pt * 4 + 3];
        out[((size_t)b * 64 + o) * NPTS + n0 + pt] =
            fmaxf(fmaxf(m0_, m1), fmaxf(m2, m3));
    }
}

// ---------------------------------------------------------------------------
extern "C" void kernel_launch(void* const* d_in, const int* in_sizes, int n_in,
                              void* d_out, int out_size, void* d_ws, size_t ws_size,
                              hipStream_t stream) {
    const float* xyz = (const float*)d_in[0];
    const float* fea = (const float*)d_in[1];
    const float* Wg1 = (const float*)d_in[2];
    const float* bg1 = (const float*)d_in[3];
    const float* Wg2 = (const float*)d_in[4];
    const float* bg2 = (const float*)d_in[5];
    const float* Wf1 = (const float*)d_in[6];
    const float* bf1 = (const float*)d_in[7];
    const float* Wf2 = (const float*)d_in[8];
    const float* bf2 = (const float*)d_in[9];
    const float* Wf3 = (const float*)d_in[10];
    const float* bf3 = (const float*)d_in[11];
    float* out = (float*)d_out;
    float* ws = (float*)d_ws;

    float* sq = ws + WS_SQ;
    float* Pt = ws + WS_PT;
    float* Qt = ws + WS_QT;
    int* idxw = (int*)(ws + WS_IDX);

    k_sq <<<dim3(128),      dim3(256), 0, stream>>>(fea, sq);
    k_knn<<<dim3(64, 8),    dim3(256), 0, stream>>>(fea, sq, idxw);
    k_pq <<<dim3(64, 8),    dim3(256), 0, stream>>>(fea, Wf1, bf1, Pt, Qt);
    k_mlp<<<dim3(1024, 8),  dim3(256), 0, stream>>>(xyz, Pt, Qt, idxw,
                                                    Wg1, bg1, Wg2, bg2,
                                                    Wf2, bf2, Wf3, bf3, out);
}

// Round 2
// 1427.160 us; speedup vs baseline: 1.2215x; 1.2215x over previous
//
#include <hip/hip_runtime.h>
#include <math.h>

#define NB 8
#define NPTS 4096
#define NCH 64
#define NOUT 64
#define KNN 16

// ws layout in floats:
#define WS_SQ  0
#define WS_PT  (NB*NPTS)                       // 32768
#define WS_QT  (WS_PT + NB*NPTS*64)            // + 2097152
#define WS_IDX (WS_QT + NB*NPTS*64)            // int32 region, NB*NPTS*16 ints

// ---------------------------------------------------------------- K1: sq ----
__global__ __launch_bounds__(256) void k_sq(const float* __restrict__ fea,
                                            float* __restrict__ sq) {
    int g = blockIdx.x * 256 + threadIdx.x;      // 32768
    int b = g >> 12, n = g & 4095;
    const float* f = fea + (size_t)b * NCH * NPTS + n;
    float s = 0.f;
#pragma unroll
    for (int c = 0; c < NCH; ++c) s = fmaf(f[c * NPTS], f[c * NPTS], s);
    sq[g] = s;
}

// ------------------------------------------------------- K2: fused KNN ------
// 64 rows/block. Gram tile 64x64 via 4x4 register micro-tiles.
// Top-k: 2 slice-lists per row (cols 0-31 / 32-63 of each tile), maintained by
// 128 threads in parallel; stride-17 lists (conflict-free); merge at end.
// colT and dist share one 16KB buffer; dist stored with XOR swizzle
// colp = col ^ (((row>>3)&7)<<2) to break stride-64 bank aliasing.
__global__ __launch_bounds__(256) void k_knn(const float* __restrict__ fea,
                                             const float* __restrict__ sq,
                                             int* __restrict__ idxout) {
    __shared__ __align__(16) float rowT[64][64];   // [c][r]
    __shared__ __align__(16) float U[64 * 64];     // colT [c][j] then dist [r][jswz]
    __shared__ float tkv[2][64][17];
    __shared__ int   tki[2][64][17];

    const int b = blockIdx.y;
    const int n0 = blockIdx.x * 64;
    const int tid = threadIdx.x;
    const int to = tid & 15, tp = tid >> 4;
    const int srow = tid & 63, ss = tid >> 6;      // scan assignment
    const float* feab = fea + (size_t)b * NCH * NPTS;

#pragma unroll
    for (int i = 0; i < 4; ++i) {
        int e = i * 1024 + tid * 4;
        int c = e >> 6, r = e & 63;
        *(float4*)&rowT[c][r] = *(const float4*)&feab[c * NPTS + n0 + r];
    }
    if (ss < 2) {
#pragma unroll
        for (int i = 0; i < KNN; ++i) { tkv[ss][srow][i] = -3.0e38f; tki[ss][srow][i] = 0; }
    }

    for (int m0 = 0; m0 < NPTS; m0 += 64) {
        __syncthreads();                            // prev scan done; U reusable
#pragma unroll
        for (int i = 0; i < 4; ++i) {
            int e = i * 1024 + tid * 4;
            int c = e >> 6, j = e & 63;
            *(float4*)&U[c * 64 + j] = *(const float4*)&feab[c * NPTS + m0 + j];
        }
        __syncthreads();

        float acc[4][4] = {{0.f,0.f,0.f,0.f},{0.f,0.f,0.f,0.f},
                           {0.f,0.f,0.f,0.f},{0.f,0.f,0.f,0.f}};
#pragma unroll 8
        for (int c = 0; c < 64; ++c) {
            float4 rv = *(const float4*)&rowT[c][to * 4];
            float4 cv = *(const float4*)&U[c * 64 + tp * 4];
            float rr[4] = {rv.x, rv.y, rv.z, rv.w};
            float cc[4] = {cv.x, cv.y, cv.z, cv.w};
#pragma unroll
            for (int ri = 0; ri < 4; ++ri)
#pragma unroll
                for (int ci = 0; ci < 4; ++ci)
                    acc[ri][ci] = fmaf(rr[ri], cc[ci], acc[ri][ci]);
        }
        __syncthreads();                            // colT fully consumed

        float4 sqc = *(const float4*)&sq[b * NPTS + m0 + tp * 4];
        float sqa[4] = {sqc.x, sqc.y, sqc.z, sqc.w};
#pragma unroll
        for (int ri = 0; ri < 4; ++ri) {
            int row = to * 4 + ri;
            int colp = (tp * 4) ^ (((row >> 3) & 7) << 2);  // bits 0-1 preserved
            float4 o;
            o.x = 2.f * acc[ri][0] - sqa[0];
            o.y = 2.f * acc[ri][1] - sqa[1];
            o.z = 2.f * acc[ri][2] - sqa[2];
            o.w = 2.f * acc[ri][3] - sqa[3];
            *(float4*)&U[row * 64 + colp] = o;
        }
        __syncthreads();

        if (ss < 2) {                               // 128 threads: 2 slices/row
            float thr = tkv[ss][srow][0];
            const int swz = ((srow >> 3) & 7) << 2;
            for (int jj = 0; jj < 32; ++jj) {
                int cl = ss * 32 + ((jj + srow) & 31);   // logical col
                float v = U[srow * 64 + (cl ^ swz)];
                if (v > thr) {
                    int p = 0;
                    while (p < KNN - 1 && tkv[ss][srow][p + 1] < v) {
                        tkv[ss][srow][p] = tkv[ss][srow][p + 1];
                        tki[ss][srow][p] = tki[ss][srow][p + 1];
                        ++p;
                    }
                    tkv[ss][srow][p] = v; tki[ss][srow][p] = m0 + cl;
                    thr = tkv[ss][srow][0];
                }
            }
        }
    }
    __syncthreads();

    if (tid < 64) {                                 // merge two sorted lists
        const int r = tid;
        int p0 = KNN - 1, p1 = KNN - 1;
        size_t obase = ((size_t)(b * NPTS) + n0 + r) * KNN;
        for (int i = 0; i < KNN; ++i) {
            float v0 = (p0 >= 0) ? tkv[0][r][p0] : -3.9e38f;
            float v1 = (p1 >= 0) ? tkv[1][r][p1] : -3.9e38f;
            int i0 = (p0 >= 0) ? tki[0][r][p0] : 0x7fffffff;
            int i1 = (p1 >= 0) ? tki[1][r][p1] : 0x7fffffff;
            bool take0 = (v0 > v1) || (v0 == v1 && i0 < i1);
            idxout[obase + i] = take0 ? i0 : i1;
            if (take0) --p0; else --p1;
        }
    }
}

// ----------------------------------------------- K3: P/Q precompute ---------
__global__ __launch_bounds__(256) void k_pq(const float* __restrict__ fea,
                                            const float* __restrict__ Wf1,
                                            const float* __restrict__ bf1,
                                            float* __restrict__ Pt,
                                            float* __restrict__ Qt) {
    __shared__ __align__(16) float feaT[64][64];    // [c][n]
    __shared__ __align__(16) float WT[64][132];     // [c][o'], o' in 0..127
    __shared__ float sb[64];

    const int b = blockIdx.y;
    const int n0 = blockIdx.x * 64;
    const int tid = threadIdx.x;
    const int to = tid & 15, tn = tid >> 4;
    const float* feab = fea + (size_t)b * NCH * NPTS;

#pragma unroll
    for (int i = 0; i < 4; ++i) {
        int e = i * 1024 + tid * 4;
        int c = e >> 6, nn = e & 63;
        *(float4*)&feaT[c][nn] = *(const float4*)&feab[c * NPTS + n0 + nn];
    }
#pragma unroll
    for (int i = 0; i < 8; ++i) {
        int g = tid * 32 + i * 4;
        int op = g >> 6, c = g & 63;
        const float* src = (op < 64) ? &Wf1[op * 128 + c]
                                     : &Wf1[(op - 64) * 128 + 64 + c];
        float4 w = *(const float4*)src;
        WT[c + 0][op] = w.x; WT[c + 1][op] = w.y;
        WT[c + 2][op] = w.z; WT[c + 3][op] = w.w;
    }
    if (tid < 64) sb[tid] = bf1[tid];
    __syncthreads();

    float acc[4][8];
#pragma unroll
    for (int ni = 0; ni < 4; ++ni)
#pragma unroll
        for (int oj = 0; oj < 8; ++oj) acc[ni][oj] = 0.f;

#pragma unroll 4
    for (int c = 0; c < 64; ++c) {
        float4 a  = *(const float4*)&feaT[c][tn * 4];
        float4 w0 = *(const float4*)&WT[c][to * 8];
        float4 w1 = *(const float4*)&WT[c][to * 8 + 4];
        float av[4] = {a.x, a.y, a.z, a.w};
        float wv[8] = {w0.x, w0.y, w0.z, w0.w, w1.x, w1.y, w1.z, w1.w};
#pragma unroll
        for (int ni = 0; ni < 4; ++ni)
#pragma unroll
            for (int oj = 0; oj < 8; ++oj)
                acc[ni][oj] = fmaf(av[ni], wv[oj], acc[ni][oj]);
    }

    const int opb = to * 8;
#pragma unroll
    for (int ni = 0; ni < 4; ++ni) {
        int n = n0 + tn * 4 + ni;
        size_t base = ((size_t)b * NPTS + n) * 64;
        if (opb < 64) {     // P half: add bias
            float4 o0, o1;
            o0.x = acc[ni][0] + sb[opb + 0]; o0.y = acc[ni][1] + sb[opb + 1];
            o0.z = acc[ni][2] + sb[opb + 2]; o0.w = acc[ni][3] + sb[opb + 3];
            o1.x = acc[ni][4] + sb[opb + 4]; o1.y = acc[ni][5] + sb[opb + 5];
            o1.z = acc[ni][6] + sb[opb + 6]; o1.w = acc[ni][7] + sb[opb + 7];
            *(float4*)&Pt[base + opb]     = o0;
            *(float4*)&Pt[base + opb + 4] = o1;
        } else {            // Q half: no bias
            float4 o0, o1;
            o0.x = acc[ni][0]; o0.y = acc[ni][1]; o0.z = acc[ni][2]; o0.w = acc[ni][3];
            o1.x = acc[ni][4]; o1.y = acc[ni][5]; o1.z = acc[ni][6]; o1.w = acc[ni][7];
            *(float4*)&Qt[base + opb - 64]     = o0;
            *(float4*)&Qt[base + opb - 64 + 4] = o1;
        }
    }
}

// -------------------------------------------- K4: fused MLP + max ----------
__global__ __launch_bounds__(256) void k_mlp(
    const float* __restrict__ xyz,
    const float* __restrict__ Pt, const float* __restrict__ Qt,
    const int* __restrict__ knnidx,
    const float* __restrict__ Wg1, const float* __restrict__ bg1,
    const float* __restrict__ Wg2, const float* __restrict__ bg2,
    const float* __restrict__ Wf2, const float* __restrict__ bf2,
    const float* __restrict__ Wf3, const float* __restrict__ bf3,
    float* __restrict__ out) {
    __shared__ __align__(16) float bufX[64][68];
    __shared__ __align__(16) float bufY[64][68];
    __shared__ __align__(16) float Wbuf[64][68];
    __shared__ __align__(16) float scratch[1280];  // geo[10][68] then pm[64][17]
    __shared__ float biasS[64];
    __shared__ int sidx[64];

    const int b = blockIdx.y;
    const int n0 = blockIdx.x * 4;
    const int tid = threadIdx.x;
    const int to = tid & 15, tp = tid >> 4;

    if (tid < 64)
        sidx[tid] = knnidx[((size_t)(b * NPTS + n0)) * KNN + tid];
    __syncthreads();

    // f1 = relu(P + Q_gather) into bufX [c][pair]
    {
        int pair = tid >> 2, q = tid & 3;
        int m = sidx[pair];
        int pt = pair >> 4;
        const float* pB = &Pt[((size_t)b * NPTS + n0 + pt) * 64];
        const float* qB = &Qt[((size_t)b * NPTS + m) * 64];
#pragma unroll
        for (int i = 0; i < 4; ++i) {
            int c0 = q * 16 + i * 4;
            float4 pv = *(const float4*)&pB[c0];
            float4 qv = *(const float4*)&qB[c0];
            bufX[c0 + 0][pair] = fmaxf(pv.x + qv.x, 0.f);
            bufX[c0 + 1][pair] = fmaxf(pv.y + qv.y, 0.f);
            bufX[c0 + 2][pair] = fmaxf(pv.z + qv.z, 0.f);
            bufX[c0 + 3][pair] = fmaxf(pv.w + qv.w, 0.f);
        }
    }
    // geo [10][68] into scratch
    if (tid < 64) {
        int pair = tid, pt = pair >> 4;
        int m = sidx[pair];
        const float* xb = xyz + (size_t)b * 3 * NPTS;
        float cx = xb[0 * NPTS + n0 + pt], cy = xb[1 * NPTS + n0 + pt], cz = xb[2 * NPTS + n0 + pt];
        float kx = xb[0 * NPTS + m], ky = xb[1 * NPTS + m], kz = xb[2 * NPTS + m];
        float rx = cx - kx, ry = cy - ky, rz = cz - kz;
        float d = sqrtf(rx * rx + ry * ry + rz * rz);
        scratch[0 * 68 + pair] = d;
        scratch[1 * 68 + pair] = cx; scratch[2 * 68 + pair] = cy; scratch[3 * 68 + pair] = cz;
        scratch[4 * 68 + pair] = kx; scratch[5 * 68 + pair] = ky; scratch[6 * 68 + pair] = kz;
        scratch[7 * 68 + pair] = rx; scratch[8 * 68 + pair] = ry; scratch[9 * 68 + pair] = rz;
    }

    auto stageW = [&](const float* W, const float* bv) {
#pragma unroll
        for (int i = 0; i < 4; ++i) {
            int g = tid * 16 + i * 4;
            int o = g >> 6, c = g & 63;
            float4 w = *(const float4*)&W[g];
            Wbuf[c + 0][o] = w.x; Wbuf[c + 1][o] = w.y;
            Wbuf[c + 2][o] = w.z; Wbuf[c + 3][o] = w.w;
        }
        if (tid < 64) biasS[tid] = bv[tid];
    };

    auto gemmPh = [&](const float* src, float* dst, int Kdim) {
        float acc[4][4] = {{0.f,0.f,0.f,0.f},{0.f,0.f,0.f,0.f},
                           {0.f,0.f,0.f,0.f},{0.f,0.f,0.f,0.f}};
#pragma unroll 2
        for (int c = 0; c < Kdim; ++c) {
            float4 w = *(const float4*)&Wbuf[c][to * 4];
            float4 a = *(const float4*)(src + c * 68 + tp * 4);
            float wr[4] = {w.x, w.y, w.z, w.w};
            float ar[4] = {a.x, a.y, a.z, a.w};
#pragma unroll
            for (int oi = 0; oi < 4; ++oi)
#pragma unroll
                for (int pj = 0; pj < 4; ++pj)
                    acc[oi][pj] = fmaf(wr[oi], ar[pj], acc[oi][pj]);
        }
#pragma unroll
        for (int oi = 0; oi < 4; ++oi) {
            float bo = biasS[to * 4 + oi];
            float4 o4;
            o4.x = fmaxf(acc[oi][0] + bo, 0.f);
            o4.y = fmaxf(acc[oi][1] + bo, 0.f);
            o4.z = fmaxf(acc[oi][2] + bo, 0.f);
            o4.w = fmaxf(acc[oi][3] + bo, 0.f);
            *(float4*)(dst + (to * 4 + oi) * 68 + tp * 4) = o4;
        }
    };

    stageW(Wf2, bf2);
    __syncthreads();
    gemmPh(&bufX[0][0], &bufY[0][0], 64);       // f2
    __syncthreads();
    stageW(Wf3, bf3);
    __syncthreads();
    gemmPh(&bufY[0][0], &bufX[0][0], 64);       // f3 -> bufX
    __syncthreads();
    {   // Wg1 is 64x10
        for (int e = tid; e < 640; e += 256) {
            int o = e / 10, c = e - o * 10;
            Wbuf[c][o] = Wg1[e];
        }
        if (tid < 64) biasS[tid] = bg1[tid];
    }
    __syncthreads();
    gemmPh(scratch, &bufY[0][0], 10);           // g1 -> bufY
    __syncthreads();
    stageW(Wg2, bg2);
    __syncthreads();
    {   // g2 GEMM with fused *f3 and partial max epilogue
        float acc[4][4] = {{0.f,0.f,0.f,0.f},{0.f,0.f,0.f,0.f},
                           {0.f,0.f,0.f,0.f},{0.f,0.f,0.f,0.f}};
#pragma unroll 2
        for (int c = 0; c < 64; ++c) {
            float4 w = *(const float4*)&Wbuf[c][to * 4];
            float4 a = *(const float4*)&bufY[c][tp * 4];
            float wr[4] = {w.x, w.y, w.z, w.w};
            float ar[4] = {a.x, a.y, a.z, a.w};
#pragma unroll
            for (int oi = 0; oi < 4; ++oi)
#pragma unroll
                for (int pj = 0; pj < 4; ++pj)
                    acc[oi][pj] = fmaf(wr[oi], ar[pj], acc[oi][pj]);
        }
#pragma unroll
        for (int oi = 0; oi < 4; ++oi) {
            int o = to * 4 + oi;
            float bo = biasS[o];
            float mx = -3.0e38f;
#pragma unroll
            for (int pj = 0; pj < 4; ++pj) {
                float g2v = fmaxf(acc[oi][pj] + bo, 0.f);
                float f3v = bufX[o][tp * 4 + pj];
                mx = fmaxf(mx, g2v * f3v);
            }
            scratch[o * 17 + tp] = mx;          // pm[64][17]
        }
    }
    __syncthreads();
    {
        int o = tid & 63, pt = tid >> 6;
        float m0_ = scratch[o * 17 + pt * 4 + 0];
        float m1  = scratch[o * 17 + pt * 4 + 1];
        float m2  = scratch[o * 17 + pt * 4 + 2];
        float m3  = scratch[o * 17 + pt * 4 + 3];
        out[((size_t)b * 64 + o) * NPTS + n0 + pt] =
            fmaxf(fmaxf(m0_, m1), fmaxf(m2, m3));
    }
}

// ---------------------------------------------------------------------------
extern "C" void kernel_launch(void* const* d_in, const int* in_sizes, int n_in,
                              void* d_out, int out_size, void* d_ws, size_t ws_size,
                              hipStream_t stream) {
    const float* xyz = (const float*)d_in[0];
    const float* fea = (const float*)d_in[1];
    const float* Wg1 = (const float*)d_in[2];
    const float* bg1 = (const float*)d_in[3];
    const float* Wg2 = (const float*)d_in[4];
    const float* bg2 = (const float*)d_in[5];
    const float* Wf1 = (const float*)d_in[6];
    const float* bf1 = (const float*)d_in[7];
    const float* Wf2 = (const float*)d_in[8];
    const float* bf2 = (const float*)d_in[9];
    const float* Wf3 = (const float*)d_in[10];
    const float* bf3 = (const float*)d_in[11];
    float* out = (float*)d_out;
    float* ws = (float*)d_ws;

    float* sq = ws + WS_SQ;
    float* Pt = ws + WS_PT;
    float* Qt = ws + WS_QT;
    int* idxw = (int*)(ws + WS_IDX);

    k_sq <<<dim3(128),      dim3(256), 0, stream>>>(fea, sq);
    k_knn<<<dim3(64, 8),    dim3(256), 0, stream>>>(fea, sq, idxw);
    k_pq <<<dim3(64, 8),    dim3(256), 0, stream>>>(fea, Wf1, bf1, Pt, Qt);
    k_mlp<<<dim3(1024, 8),  dim3(256), 0, stream>>>(xyz, Pt, Qt, idxw,
                                                    Wg1, bg1, Wg2, bg2,
                                                    Wf2, bf2, Wf3, bf3, out);
}

// Round 3
// 921.500 us; speedup vs baseline: 1.8918x; 1.5487x over previous
//
#include <hip/hip_runtime.h>
#include <math.h>

#define NB 8
#define NPTS 4096
#define NCH 64
#define NOUT 64
#define KNN 16

// ws layout in floats:
#define WS_SQ  0
#define WS_PT  (NB*NPTS)                       // 32768
#define WS_QT  (WS_PT + NB*NPTS*64)            // + 2097152
#define WS_IDX (WS_QT + NB*NPTS*64)            // int32 region, NB*NPTS*16 ints

// ---------------------------------------------------------------- K1: sq ----
__global__ __launch_bounds__(256) void k_sq(const float* __restrict__ fea,
                                            float* __restrict__ sq) {
    int g = blockIdx.x * 256 + threadIdx.x;      // 32768
    int b = g >> 12, n = g & 4095;
    const float* f = fea + (size_t)b * NCH * NPTS + n;
    float s = 0.f;
#pragma unroll
    for (int c = 0; c < NCH; ++c) s = fmaf(f[c * NPTS], f[c * NPTS], s);
    sq[g] = s;
}

// ------------------------------------------------------- K2: fused KNN ------
// 64 rows/block, gram tile 64x64 (4x4 register micro-tiles, fp32 VALU).
// Top-k: each wave owns 16 rows; per-row top-16 list held ASCENDING in
// registers distributed across lanes 0..15 (compile-time row unroll).
// Scan: 64 lanes read one dist row; __ballot threshold filter; candidates
// popped via wave-uniform ffs loop; insertion = shfl_down shift (1 instr)
// + 2 predicated writes. No LDS lists, no divergent per-thread loops.
__global__ __launch_bounds__(256) void k_knn(const float* __restrict__ fea,
                                             const float* __restrict__ sq,
                                             int* __restrict__ idxout) {
    __shared__ __align__(16) float rowT[64][64];   // [c][r]
    __shared__ __align__(16) float colT[64 * 64];  // [c][j]
    __shared__ __align__(16) float D[64 * 64];     // dist [r][col^swz(r)]

    const int b = blockIdx.y;
    const int n0 = blockIdx.x * 64;
    const int tid = threadIdx.x;
    const int to = tid & 15, tp = tid >> 4;
    const int lane = tid & 63, w = tid >> 6;
    const float* feab = fea + (size_t)b * NCH * NPTS;

#pragma unroll
    for (int i = 0; i < 4; ++i) {
        int e = i * 1024 + tid * 4;
        int c = e >> 6, r = e & 63;
        *(float4*)&rowT[c][r] = *(const float4*)&feab[c * NPTS + n0 + r];
    }

    float lstv[16];                                 // row w*16+r list, lanes 0..15
    int   lsti[16];
#pragma unroll
    for (int r = 0; r < 16; ++r) { lstv[r] = -3.0e38f; lsti[r] = 0; }

    for (int m0 = 0; m0 < NPTS; m0 += 64) {
        __syncthreads();                            // prev gram consumed colT
#pragma unroll
        for (int i = 0; i < 4; ++i) {
            int e = i * 1024 + tid * 4;
            int c = e >> 6, j = e & 63;
            *(float4*)&colT[c * 64 + j] = *(const float4*)&feab[c * NPTS + m0 + j];
        }
        __syncthreads();

        float acc[4][4] = {{0.f,0.f,0.f,0.f},{0.f,0.f,0.f,0.f},
                           {0.f,0.f,0.f,0.f},{0.f,0.f,0.f,0.f}};
#pragma unroll 8
        for (int c = 0; c < 64; ++c) {
            float4 rv = *(const float4*)&rowT[c][to * 4];
            float4 cv = *(const float4*)&colT[c * 64 + tp * 4];
            float rr[4] = {rv.x, rv.y, rv.z, rv.w};
            float cc[4] = {cv.x, cv.y, cv.z, cv.w};
#pragma unroll
            for (int ri = 0; ri < 4; ++ri)
#pragma unroll
                for (int ci = 0; ci < 4; ++ci)
                    acc[ri][ci] = fmaf(rr[ri], cc[ci], acc[ri][ci]);
        }

        float4 sqc = *(const float4*)&sq[b * NPTS + m0 + tp * 4];
        float sqa[4] = {sqc.x, sqc.y, sqc.z, sqc.w};
#pragma unroll
        for (int ri = 0; ri < 4; ++ri) {
            int row = to * 4 + ri;
            int colp = (tp * 4) ^ (((row >> 3) & 7) << 2);  // bits 0-1 preserved
            float4 o;
            o.x = 2.f * acc[ri][0] - sqa[0];
            o.y = 2.f * acc[ri][1] - sqa[1];
            o.z = 2.f * acc[ri][2] - sqa[2];
            o.w = 2.f * acc[ri][3] - sqa[3];
            *(float4*)&D[row * 64 + colp] = o;
        }
        __syncthreads();                            // D ready; scan of prev tile
                                                    // finished before loop top
#pragma unroll
        for (int r = 0; r < 16; ++r) {
            const int row = w * 16 + r;
            const int swz = ((row >> 3) & 7) << 2;
            float v = D[row * 64 + (lane ^ swz)];   // lane l holds logical col l
            float thr = __shfl(lstv[r], 0);
            unsigned long long mask = __ballot(v > thr);
            while (mask) {                          // wave-uniform loop
                int src = __ffsll((unsigned long long)mask) - 1;
                mask &= mask - 1;
                float vv = __shfl(v, src);
                if (vv > thr) {                     // uniform branch
                    int col = m0 + src;
                    unsigned long long lt =
                        __ballot((lane < 16) && (lstv[r] < vv));
                    int p = __popcll(lt);           // insertion pos, p >= 1
                    float nv = __shfl_down(lstv[r], 1);
                    int   ni = __shfl_down(lsti[r], 1);
                    if (lane <= p - 2)      { lstv[r] = nv; lsti[r] = ni; }
                    else if (lane == p - 1) { lstv[r] = vv; lsti[r] = col; }
                    thr = __shfl(lstv[r], 0);
                }
            }
        }
    }

#pragma unroll
    for (int r = 0; r < 16; ++r) {                  // descending output
        int row = w * 16 + r;
        if (lane < 16)
            idxout[((size_t)(b * NPTS) + n0 + row) * KNN + (15 - lane)] = lsti[r];
    }
}

// ----------------------------------------------- K3: P/Q precompute ---------
__global__ __launch_bounds__(256) void k_pq(const float* __restrict__ fea,
                                            const float* __restrict__ Wf1,
                                            const float* __restrict__ bf1,
                                            float* __restrict__ Pt,
                                            float* __restrict__ Qt) {
    __shared__ __align__(16) float feaT[64][64];    // [c][n]
    __shared__ __align__(16) float WT[64][132];     // [c][o'], o' in 0..127
    __shared__ float sb[64];

    const int b = blockIdx.y;
    const int n0 = blockIdx.x * 64;
    const int tid = threadIdx.x;
    const int to = tid & 15, tn = tid >> 4;
    const float* feab = fea + (size_t)b * NCH * NPTS;

#pragma unroll
    for (int i = 0; i < 4; ++i) {
        int e = i * 1024 + tid * 4;
        int c = e >> 6, nn = e & 63;
        *(float4*)&feaT[c][nn] = *(const float4*)&feab[c * NPTS + n0 + nn];
    }
#pragma unroll
    for (int i = 0; i < 8; ++i) {
        int g = tid * 32 + i * 4;
        int op = g >> 6, c = g & 63;
        const float* src = (op < 64) ? &Wf1[op * 128 + c]
                                     : &Wf1[(op - 64) * 128 + 64 + c];
        float4 w = *(const float4*)src;
        WT[c + 0][op] = w.x; WT[c + 1][op] = w.y;
        WT[c + 2][op] = w.z; WT[c + 3][op] = w.w;
    }
    if (tid < 64) sb[tid] = bf1[tid];
    __syncthreads();

    float acc[4][8];
#pragma unroll
    for (int ni = 0; ni < 4; ++ni)
#pragma unroll
        for (int oj = 0; oj < 8; ++oj) acc[ni][oj] = 0.f;

#pragma unroll 4
    for (int c = 0; c < 64; ++c) {
        float4 a  = *(const float4*)&feaT[c][tn * 4];
        float4 w0 = *(const float4*)&WT[c][to * 8];
        float4 w1 = *(const float4*)&WT[c][to * 8 + 4];
        float av[4] = {a.x, a.y, a.z, a.w};
        float wv[8] = {w0.x, w0.y, w0.z, w0.w, w1.x, w1.y, w1.z, w1.w};
#pragma unroll
        for (int ni = 0; ni < 4; ++ni)
#pragma unroll
            for (int oj = 0; oj < 8; ++oj)
                acc[ni][oj] = fmaf(av[ni], wv[oj], acc[ni][oj]);
    }

    const int opb = to * 8;
#pragma unroll
    for (int ni = 0; ni < 4; ++ni) {
        int n = n0 + tn * 4 + ni;
        size_t base = ((size_t)b * NPTS + n) * 64;
        if (opb < 64) {     // P half: add bias
            float4 o0, o1;
            o0.x = acc[ni][0] + sb[opb + 0]; o0.y = acc[ni][1] + sb[opb + 1];
            o0.z = acc[ni][2] + sb[opb + 2]; o0.w = acc[ni][3] + sb[opb + 3];
            o1.x = acc[ni][4] + sb[opb + 4]; o1.y = acc[ni][5] + sb[opb + 5];
            o1.z = acc[ni][6] + sb[opb + 6]; o1.w = acc[ni][7] + sb[opb + 7];
            *(float4*)&Pt[base + opb]     = o0;
            *(float4*)&Pt[base + opb + 4] = o1;
        } else {            // Q half: no bias
            float4 o0, o1;
            o0.x = acc[ni][0]; o0.y = acc[ni][1]; o0.z = acc[ni][2]; o0.w = acc[ni][3];
            o1.x = acc[ni][4]; o1.y = acc[ni][5]; o1.z = acc[ni][6]; o1.w = acc[ni][7];
            *(float4*)&Qt[base + opb - 64]     = o0;
            *(float4*)&Qt[base + opb - 64 + 4] = o1;
        }
    }
}

// -------------------------------------------- K4: fused MLP + max ----------
__global__ __launch_bounds__(256) void k_mlp(
    const float* __restrict__ xyz,
    const float* __restrict__ Pt, const float* __restrict__ Qt,
    const int* __restrict__ knnidx,
    const float* __restrict__ Wg1, const float* __restrict__ bg1,
    const float* __restrict__ Wg2, const float* __restrict__ bg2,
    const float* __restrict__ Wf2, const float* __restrict__ bf2,
    const float* __restrict__ Wf3, const float* __restrict__ bf3,
    float* __restrict__ out) {
    __shared__ __align__(16) float bufX[64][68];
    __shared__ __align__(16) float bufY[64][68];
    __shared__ __align__(16) float Wbuf[64][68];
    __shared__ __align__(16) float scratch[1280];  // geo[10][68] then pm[64][17]
    __shared__ float biasS[64];
    __shared__ int sidx[64];

    const int b = blockIdx.y;
    const int n0 = blockIdx.x * 4;
    const int tid = threadIdx.x;
    const int to = tid & 15, tp = tid >> 4;

    if (tid < 64)
        sidx[tid] = knnidx[((size_t)(b * NPTS + n0)) * KNN + tid];
    __syncthreads();

    // f1 = relu(P + Q_gather) into bufX [c][pair]
    {
        int pair = tid >> 2, q = tid & 3;
        int m = sidx[pair];
        int pt = pair >> 4;
        const float* pB = &Pt[((size_t)b * NPTS + n0 + pt) * 64];
        const float* qB = &Qt[((size_t)b * NPTS + m) * 64];
#pragma unroll
        for (int i = 0; i < 4; ++i) {
            int c0 = q * 16 + i * 4;
            float4 pv = *(const float4*)&pB[c0];
            float4 qv = *(const float4*)&qB[c0];
            bufX[c0 + 0][pair] = fmaxf(pv.x + qv.x, 0.f);
            bufX[c0 + 1][pair] = fmaxf(pv.y + qv.y, 0.f);
            bufX[c0 + 2][pair] = fmaxf(pv.z + qv.z, 0.f);
            bufX[c0 + 3][pair] = fmaxf(pv.w + qv.w, 0.f);
        }
    }
    // geo [10][68] into scratch
    if (tid < 64) {
        int pair = tid, pt = pair >> 4;
        int m = sidx[pair];
        const float* xb = xyz + (size_t)b * 3 * NPTS;
        float cx = xb[0 * NPTS + n0 + pt], cy = xb[1 * NPTS + n0 + pt], cz = xb[2 * NPTS + n0 + pt];
        float kx = xb[0 * NPTS + m], ky = xb[1 * NPTS + m], kz = xb[2 * NPTS + m];
        float rx = cx - kx, ry = cy - ky, rz = cz - kz;
        float d = sqrtf(rx * rx + ry * ry + rz * rz);
        scratch[0 * 68 + pair] = d;
        scratch[1 * 68 + pair] = cx; scratch[2 * 68 + pair] = cy; scratch[3 * 68 + pair] = cz;
        scratch[4 * 68 + pair] = kx; scratch[5 * 68 + pair] = ky; scratch[6 * 68 + pair] = kz;
        scratch[7 * 68 + pair] = rx; scratch[8 * 68 + pair] = ry; scratch[9 * 68 + pair] = rz;
    }

    auto stageW = [&](const float* W, const float* bv) {
#pragma unroll
        for (int i = 0; i < 4; ++i) {
            int g = tid * 16 + i * 4;
            int o = g >> 6, c = g & 63;
            float4 w = *(const float4*)&W[g];
            Wbuf[c + 0][o] = w.x; Wbuf[c + 1][o] = w.y;
            Wbuf[c + 2][o] = w.z; Wbuf[c + 3][o] = w.w;
        }
        if (tid < 64) biasS[tid] = bv[tid];
    };

    auto gemmPh = [&](const float* src, float* dst, int Kdim) {
        float acc[4][4] = {{0.f,0.f,0.f,0.f},{0.f,0.f,0.f,0.f},
                           {0.f,0.f,0.f,0.f},{0.f,0.f,0.f,0.f}};
#pragma unroll 2
        for (int c = 0; c < Kdim; ++c) {
            float4 w = *(const float4*)&Wbuf[c][to * 4];
            float4 a = *(const float4*)(src + c * 68 + tp * 4);
            float wr[4] = {w.x, w.y, w.z, w.w};
            float ar[4] = {a.x, a.y, a.z, a.w};
#pragma unroll
            for (int oi = 0; oi < 4; ++oi)
#pragma unroll
                for (int pj = 0; pj < 4; ++pj)
                    acc[oi][pj] = fmaf(wr[oi], ar[pj], acc[oi][pj]);
        }
#pragma unroll
        for (int oi = 0; oi < 4; ++oi) {
            float bo = biasS[to * 4 + oi];
            float4 o4;
            o4.x = fmaxf(acc[oi][0] + bo, 0.f);
            o4.y = fmaxf(acc[oi][1] + bo, 0.f);
            o4.z = fmaxf(acc[oi][2] + bo, 0.f);
            o4.w = fmaxf(acc[oi][3] + bo, 0.f);
            *(float4*)(dst + (to * 4 + oi) * 68 + tp * 4) = o4;
        }
    };

    stageW(Wf2, bf2);
    __syncthreads();
    gemmPh(&bufX[0][0], &bufY[0][0], 64);       // f2
    __syncthreads();
    stageW(Wf3, bf3);
    __syncthreads();
    gemmPh(&bufY[0][0], &bufX[0][0], 64);       // f3 -> bufX
    __syncthreads();
    {   // Wg1 is 64x10
        for (int e = tid; e < 640; e += 256) {
            int o = e / 10, c = e - o * 10;
            Wbuf[c][o] = Wg1[e];
        }
        if (tid < 64) biasS[tid] = bg1[tid];
    }
    __syncthreads();
    gemmPh(scratch, &bufY[0][0], 10);           // g1 -> bufY
    __syncthreads();
    stageW(Wg2, bg2);
    __syncthreads();
    {   // g2 GEMM with fused *f3 and partial max epilogue
        float acc[4][4] = {{0.f,0.f,0.f,0.f},{0.f,0.f,0.f,0.f},
                           {0.f,0.f,0.f,0.f},{0.f,0.f,0.f,0.f}};
#pragma unroll 2
        for (int c = 0; c < 64; ++c) {
            float4 w = *(const float4*)&Wbuf[c][to * 4];
            float4 a = *(const float4*)&bufY[c][tp * 4];
            float wr[4] = {w.x, w.y, w.z, w.w};
            float ar[4] = {a.x, a.y, a.z, a.w};
#pragma unroll
            for (int oi = 0; oi < 4; ++oi)
#pragma unroll
                for (int pj = 0; pj < 4; ++pj)
                    acc[oi][pj] = fmaf(wr[oi], ar[pj], acc[oi][pj]);
        }
#pragma unroll
        for (int oi = 0; oi < 4; ++oi) {
            int o = to * 4 + oi;
            float bo = biasS[o];
            float mx = -3.0e38f;
#pragma unroll
            for (int pj = 0; pj < 4; ++pj) {
                float g2v = fmaxf(acc[oi][pj] + bo, 0.f);
                float f3v = bufX[o][tp * 4 + pj];
                mx = fmaxf(mx, g2v * f3v);
            }
            scratch[o * 17 + tp] = mx;          // pm[64][17]
        }
    }
    __syncthreads();
    {
        int o = tid & 63, pt = tid >> 6;
        float m0_ = scratch[o * 17 + pt * 4 + 0];
        float m1  = scratch[o * 17 + pt * 4 + 1];
        float m2  = scratch[o * 17 + pt * 4 + 2];
        float m3  = scratch[o * 17 + pt * 4 + 3];
        out[((size_t)b * 64 + o) * NPTS + n0 + pt] =
            fmaxf(fmaxf(m0_, m1), fmaxf(m2, m3));
    }
}

// ---------------------------------------------------------------------------
extern "C" void kernel_launch(void* const* d_in, const int* in_sizes, int n_in,
                              void* d_out, int out_size, void* d_ws, size_t ws_size,
                              hipStream_t stream) {
    const float* xyz = (const float*)d_in[0];
    const float* fea = (const float*)d_in[1];
    const float* Wg1 = (const float*)d_in[2];
    const float* bg1 = (const float*)d_in[3];
    const float* Wg2 = (const float*)d_in[4];
    const float* bg2 = (const float*)d_in[5];
    const float* Wf1 = (const float*)d_in[6];
    const float* bf1 = (const float*)d_in[7];
    const float* Wf2 = (const float*)d_in[8];
    const float* bf2 = (const float*)d_in[9];
    const float* Wf3 = (const float*)d_in[10];
    const float* bf3 = (const float*)d_in[11];
    float* out = (float*)d_out;
    float* ws = (float*)d_ws;

    float* sq = ws + WS_SQ;
    float* Pt = ws + WS_PT;
    float* Qt = ws + WS_QT;
    int* idxw = (int*)(ws + WS_IDX);

    k_sq <<<dim3(128),      dim3(256), 0, stream>>>(fea, sq);
    k_knn<<<dim3(64, 8),    dim3(256), 0, stream>>>(fea, sq, idxw);
    k_pq <<<dim3(64, 8),    dim3(256), 0, stream>>>(fea, Wf1, bf1, Pt, Qt);
    k_mlp<<<dim3(1024, 8),  dim3(256), 0, stream>>>(xyz, Pt, Qt, idxw,
                                                    Wg1, bg1, Wg2, bg2,
                                                    Wf2, bf2, Wf3, bf3, out);
}